// Round 16
// baseline (301.376 us; speedup 1.0000x reference)
//
#include <hip/hip_runtime.h>
#include <hip/hip_bf16.h>
#include <cstdint>
#include <cstddef>

// Problem constants (fixed by the reference)
#define BATCH 128
#define SEQ   512
#define DIM   1024
#define MROWS (BATCH * SEQ)          // 65536
#define NT    32                     // K sub-tiles of 32 (DIM/32)

typedef short short8 __attribute__((ext_vector_type(8)));
typedef __bf16 bf16x8 __attribute__((ext_vector_type(8)));
typedef float f32x4 __attribute__((ext_vector_type(4)));

// ---------- MFMA wrapper: accept either builtin signature (short8 or bf16x8) ----------
template <typename VA> struct other_frag { using type = bf16x8; };
template <> struct other_frag<bf16x8> { using type = short8; };

template <typename VA>
__device__ __forceinline__ auto try_mfma(VA a, VA b, f32x4 c, int)
    -> decltype(__builtin_amdgcn_mfma_f32_16x16x32_bf16(a, b, c, 0, 0, 0)) {
  return __builtin_amdgcn_mfma_f32_16x16x32_bf16(a, b, c, 0, 0, 0);
}
template <typename VA>
__device__ __forceinline__ f32x4 try_mfma(VA a, VA b, f32x4 c, long) {
  using O = typename other_frag<VA>::type;
  O a2 = __builtin_bit_cast(O, a);
  O b2 = __builtin_bit_cast(O, b);
  return __builtin_amdgcn_mfma_f32_16x16x32_bf16(a2, b2, c, 0, 0, 0);
}
__device__ __forceinline__ f32x4 mfma_bf16(short8 a, short8 b, f32x4 c) {
  return try_mfma(a, b, c, 0);
}

// ---------- helpers ----------
__device__ __forceinline__ unsigned short f32_to_bf16(float f) {
  union { float f; uint32_t u; } v; v.f = f;
  uint32_t u = v.u;
  u += 0x7FFFu + ((u >> 16) & 1u);   // round-to-nearest-even
  return (unsigned short)(u >> 16);
}

// 8 x f32 -> 8 x bf16 (RNE)
__device__ __forceinline__ short8 cvt8(f32x4 a, f32x4 b) {
  bf16x8 o;
  o[0] = (__bf16)a[0]; o[1] = (__bf16)a[1]; o[2] = (__bf16)a[2]; o[3] = (__bf16)a[3];
  o[4] = (__bf16)b[0]; o[5] = (__bf16)b[1]; o[6] = (__bf16)b[2]; o[7] = (__bf16)b[3];
  return __builtin_bit_cast(short8, o);
}

__device__ __forceinline__ void gload_lds16(const void* g, void* l) {
  __builtin_amdgcn_global_load_lds(
      (__attribute__((address_space(1))) void*)g,
      (__attribute__((address_space(3))) void*)l,
      16, 0, 0);
}

__device__ __forceinline__ float fast_tanh(float x) {
  x = fminf(fmaxf(x, -15.0f), 15.0f);
  float e = __expf(2.0f * x);
  return (e - 1.0f) / (e + 1.0f);
}

// ---------- kernel 1: W1 (D x D) -> W1t bf16 (transposed, [e][d]) ----------
__global__ __launch_bounds__(256) void w1t_kernel(const float* __restrict__ W1,
                                                  unsigned short* __restrict__ W1t) {
  __shared__ float tile[64][65];
  int bx = blockIdx.x & 15;    // e-tile
  int by = blockIdx.x >> 4;    // d-tile
  int t = threadIdx.x;
  int c = t & 63, r0 = t >> 6;
#pragma unroll
  for (int i = 0; i < 16; i++) {
    int r = i * 4 + r0;
    tile[r][c] = W1[(size_t)(by * 64 + r) * DIM + bx * 64 + c];
  }
  __syncthreads();
#pragma unroll
  for (int i = 0; i < 16; i++) {
    int r = i * 4 + r0;
    W1t[(size_t)(bx * 64 + r) * DIM + by * 64 + c] = f32_to_bf16(tile[c][r]);
  }
}

// ---------- kernel 2: 128x128-tile pipelined GEMM (fp32 A direct), 2 blk/CU ----------
// C[m][e] = sum_d bf16(X[m][d]) * W1t[e][d]; scores[m] += sum_e tanh(C+b1[e])*w2[e]
//
// R14's exact choreography (counted vmcnt(6) depth-2 + one raw barrier per
// K32-subtile, ring-3 buffers, R10-validated conflict-free layouts, XCD-chunked
// grid) at 128x128 tile / 4 waves (2Mx2N, wave-tile 64x64) so LDS = 72 KB ->
// 2 blocks/CU.  Rationale: R14 at 1 block/CU barrier-locks all 8 waves -> CU
// idles through every drain (MfmaUtil 23% despite LDS:MFMA cycle ratio 1.6).
// Two co-resident blocks overlap each other's stalls (m114 mechanism, the
// basis of m97's 874 TF).  Trade: per-MFMA LDS bytes rise 1.46x (duplication)
// -- capped benefit, but the overlap mechanism is untested in this skeleton
// and everything else about it is verified.
//
//   A fp32 [128 rows][32 k]: 128-B stored row, granule js = q ^ (row&7) ^
//     ((row>>3)&7); ring-3 x 16 KB.  4 gloads/thread/subtile.
//   B bf16 row-pairs in 128-B stored rows, js = ((row&1)*4+k16) ^ (srow&7);
//     ring-3 x 8 KB.  2 gloads/thread/subtile.
//   vmcnt queue at iter S top: [A(S)4,B(S)2, A(S+1)4,B(S+1)2] -> vmcnt(6).
//   Grid 4096 = 512 m-tiles x 8 n-tiles; per XCD 64 consecutive m-panels,
//   n-fastest -> A panel (512 KB) L2-resident across its 8 n-blocks.
__global__ __launch_bounds__(256, 2) void gemm_score_kernel(
    const float* __restrict__ X,              // [MROWS][DIM] fp32
    const unsigned short* __restrict__ W1t,   // [DIM][DIM]  (e-major)
    const float* __restrict__ b1,
    const float* __restrict__ w2,
    float* __restrict__ scores) {             // [MROWS]
  __shared__ __align__(16) char lds[73728];   // A: [0,48K)  B: [48K,72K)

  const int tid = threadIdx.x;
  const int lane = tid & 63;
  const int w = tid >> 6;                     // wave 0..3
  const int wr = w >> 1, wc = w & 1;          // 2 x 2 wave grid, 64x64 each

  // chunked XCD swizzle: 4096 blocks, 8 XCDs, n-fastest within each chunk
  const int bx = blockIdx.x;
  const int swz = (bx & 7) * 512 + (bx >> 3);
  const int m0 = (swz >> 3) * 128;
  const int n0 = (swz & 7) * 128;

  // ---- A staging sources: 4 chunks/thread, sc = i*256 + tid.
  // row = sc>>3, js = sc&7, q = js ^ (row&7) ^ ((row>>3)&7).
  const float* aSrc[4];
#pragma unroll
  for (int i = 0; i < 4; i++) {
    int sc = i * 256 + tid;
    int row = sc >> 3;
    int q = (sc & 7) ^ (row & 7) ^ ((row >> 3) & 7);
    aSrc[i] = X + (size_t)(m0 + row) * DIM + q * 4;
  }
  // ---- B staging sources: 2 chunks/thread, sc = i*256 + tid (16B bf16 chunks)
  const unsigned short* bSrc[2];
#pragma unroll
  for (int i = 0; i < 2; i++) {
    int sc = i * 256 + tid;
    int srow = sc >> 3;
    int j = (sc & 7) ^ (srow & 7);
    int row = srow * 2 + (j >> 2);
    bSrc[i] = W1t + (size_t)(n0 + row) * DIM + (j & 3) * 8;
  }

  // ---- fragment LDS byte offsets (R10-validated conflict-free formulas)
  int aOff[4][2];                             // A: within a 16KB fp32 buffer
#pragma unroll
  for (int mi = 0; mi < 4; mi++) {
    int row = wr * 64 + mi * 16 + (lane & 15);
    int m = (row & 7) ^ ((row >> 3) & 7);
#pragma unroll
    for (int c = 0; c < 2; c++) {
      int js = ((lane >> 4) * 2 + c) ^ m;
      aOff[mi][c] = row * 128 + js * 16;
    }
  }
  int bOff[4];                                // B: within an 8KB bf16 buffer
#pragma unroll
  for (int ni = 0; ni < 4; ni++) {
    int row = wc * 64 + ni * 16 + (lane & 15);
    int srow = row >> 1;
    int ic = ((row & 1) * 4 + (lane >> 4)) ^ (srow & 7);
    bOff[ni] = srow * 128 + ic * 16;
  }

  f32x4 acc[4][4];
#pragma unroll
  for (int mi = 0; mi < 4; mi++)
#pragma unroll
    for (int ni = 0; ni < 4; ni++)
      acc[mi][ni] = (f32x4){0.f, 0.f, 0.f, 0.f};

  short8 af[4], bfv[4];

#define STAGE(S) do {                                                   \
    const int bufA_ = ((S) % 3) * 16384;                                \
    const int bufB_ = 49152 + ((S) % 3) * 8192;                         \
    const int koF_ = (S) * 32;                                          \
    gload_lds16(aSrc[0] + koF_, lds + bufA_ + w * 1024);                \
    gload_lds16(aSrc[1] + koF_, lds + bufA_ + 4096 + w * 1024);         \
    gload_lds16(aSrc[2] + koF_, lds + bufA_ + 8192 + w * 1024);         \
    gload_lds16(aSrc[3] + koF_, lds + bufA_ + 12288 + w * 1024);        \
    gload_lds16(bSrc[0] + koF_, lds + bufB_ + w * 1024);                \
    gload_lds16(bSrc[1] + koF_, lds + bufB_ + 4096 + w * 1024);         \
  } while (0)

#define KITER(S, VMSTR) do {                                            \
    asm volatile("s_waitcnt vmcnt(" VMSTR ")" ::: "memory");            \
    __builtin_amdgcn_s_barrier();                                       \
    __builtin_amdgcn_sched_barrier(0);                                  \
    if ((S) + 2 < NT) STAGE((S) + 2);                                   \
    const char* bufA_ = lds + ((S) % 3) * 16384;                        \
    const char* bufB_ = lds + 49152 + ((S) % 3) * 8192;                 \
    _Pragma("unroll")                                                   \
    for (int mi = 0; mi < 4; mi++) {                                    \
      f32x4 lo_ = *(const f32x4*)(bufA_ + aOff[mi][0]);                 \
      f32x4 hi_ = *(const f32x4*)(bufA_ + aOff[mi][1]);                 \
      af[mi] = cvt8(lo_, hi_);                                          \
    }                                                                   \
    _Pragma("unroll")                                                   \
    for (int ni = 0; ni < 4; ni++)                                      \
      bfv[ni] = *(const short8*)(bufB_ + bOff[ni]);                     \
    __builtin_amdgcn_s_setprio(1);                                      \
    _Pragma("unroll")                                                   \
    for (int mi = 0; mi < 4; mi++)                                      \
      _Pragma("unroll")                                                 \
      for (int ni = 0; ni < 4; ni++)                                    \
        acc[mi][ni] = mfma_bf16(af[mi], bfv[ni], acc[mi][ni]);          \
    __builtin_amdgcn_s_setprio(0);                                      \
  } while (0)

  // prologue: 2 sub-tiles in flight (12 thread-loads)
  STAGE(0); STAGE(1);

  for (int s = 0; s < NT - 1; ++s) KITER(s, "6");
  KITER(NT - 1, "0");

#undef STAGE
#undef KITER

  // epilogue: scores[row] += sum over this wave's 64 cols of tanh(c + b1) * w2
  const int cg = lane >> 4;   // row group: rows cg*4 + j
  const int cl = lane & 15;   // col within fragment
#pragma unroll
  for (int mi = 0; mi < 4; mi++) {
    float p0 = 0.f, p1 = 0.f, p2 = 0.f, p3 = 0.f;
#pragma unroll
    for (int ni = 0; ni < 4; ni++) {
      int col = n0 + wc * 64 + ni * 16 + cl;
      float w2v = w2[col];
      float b1v = b1[col];
      p0 += fast_tanh(acc[mi][ni][0] + b1v) * w2v;
      p1 += fast_tanh(acc[mi][ni][1] + b1v) * w2v;
      p2 += fast_tanh(acc[mi][ni][2] + b1v) * w2v;
      p3 += fast_tanh(acc[mi][ni][3] + b1v) * w2v;
    }
#pragma unroll
    for (int off = 1; off < 16; off <<= 1) {
      p0 += __shfl_xor(p0, off);
      p1 += __shfl_xor(p1, off);
      p2 += __shfl_xor(p2, off);
      p3 += __shfl_xor(p3, off);
    }
    if (cl == 0) {
      int row = m0 + wr * 64 + mi * 16 + cg * 4;
      atomicAdd(&scores[row + 0], p0);
      atomicAdd(&scores[row + 1], p1);
      atomicAdd(&scores[row + 2], p2);
      atomicAdd(&scores[row + 3], p3);
    }
  }
}

// ---------- kernel 3: masked softmax + u_att + u_last (fp32 X) ----------
__global__ __launch_bounds__(256) void attn_uatt_kernel(
    const float* __restrict__ X,
    const float* __restrict__ scores,
    const int* __restrict__ mask,
    float* __restrict__ u_att,
    float* __restrict__ u_last) {
  const int b = blockIdx.x;
  const int half = blockIdx.y;            // d-range [half*512, half*512+512)
  const int tid = threadIdx.x;
  const int lane = tid & 63;
  const int wave = tid >> 6;

  __shared__ float attn[SEQ];
  __shared__ float rbuf[4];
  __shared__ float part[3][64 * 9];       // padded stride 9

  float s0 = scores[(size_t)b * SEQ + tid];
  float s1 = scores[(size_t)b * SEQ + 256 + tid];
  if (mask[(size_t)b * SEQ + tid]) s0 = -1000000000.0f;
  if (mask[(size_t)b * SEQ + 256 + tid]) s1 = -1000000000.0f;

  float mx = fmaxf(s0, s1);
#pragma unroll
  for (int off = 1; off < 64; off <<= 1) mx = fmaxf(mx, __shfl_xor(mx, off));
  if (lane == 0) rbuf[wave] = mx;
  __syncthreads();
  mx = fmaxf(fmaxf(rbuf[0], rbuf[1]), fmaxf(rbuf[2], rbuf[3]));

  float p0 = expf(s0 - mx), p1 = expf(s1 - mx);
  float sm = p0 + p1;
#pragma unroll
  for (int off = 1; off < 64; off <<= 1) sm += __shfl_xor(sm, off);
  __syncthreads();
  if (lane == 0) rbuf[wave] = sm;
  __syncthreads();
  sm = rbuf[0] + rbuf[1] + rbuf[2] + rbuf[3];
  float inv = 1.0f / sm;
  attn[tid] = p0 * inv;
  attn[tid + 256] = p1 * inv;
  __syncthreads();

  // u_last: exact fp32 copy of X[:, 511, :] (this block's 512-d half)
  if (tid < 128) {
    ((f32x4*)u_last)[(size_t)b * 256 + half * 128 + tid] =
        ((const f32x4*)X)[((size_t)b * SEQ + (SEQ - 1)) * 256 + half * 128 + tid];
  }

  // u_att[b][d] = sum_s attn[s] * X[b][s][d]; block covers 512 d (64 groups of 8)
  const int col = tid & 63;            // 8-float group within the half
  const int sh = tid >> 6;             // s-range split: [sh*128, sh*128+128)
  const f32x4* Xp = (const f32x4*)X + (size_t)b * SEQ * 256 + half * 128 + col * 2;
  f32x4 a0 = {0.f, 0.f, 0.f, 0.f}, a1 = {0.f, 0.f, 0.f, 0.f};
  for (int s = sh * 128; s < sh * 128 + 128; s++) {
    float wgt = attn[s];
    a0 += wgt * Xp[(size_t)s * 256];
    a1 += wgt * Xp[(size_t)s * 256 + 1];
  }
  if (sh) {
#pragma unroll
    for (int j = 0; j < 4; j++) part[sh - 1][col * 9 + j] = a0[j];
#pragma unroll
    for (int j = 0; j < 4; j++) part[sh - 1][col * 9 + 4 + j] = a1[j];
  }
  __syncthreads();
  if (sh == 0) {
#pragma unroll
    for (int j = 0; j < 4; j++)
      a0[j] += part[0][col * 9 + j] + part[1][col * 9 + j] + part[2][col * 9 + j];
#pragma unroll
    for (int j = 0; j < 4; j++)
      a1[j] += part[0][col * 9 + 4 + j] + part[1][col * 9 + 4 + j] + part[2][col * 9 + 4 + j];
    f32x4* dst = (f32x4*)(u_att + (size_t)b * DIM + half * 512 + col * 8);
    dst[0] = a0;
    dst[1] = a1;
  }
}

// ---------- launcher ----------
extern "C" void kernel_launch(void* const* d_in, const int* in_sizes, int n_in,
                              void* d_out, int out_size, void* d_ws, size_t ws_size,
                              hipStream_t stream) {
  const float* X    = (const float*)d_in[0];   // [128][512][1024] fp32
  const int*   mask = (const int*)d_in[1];     // [128][512] int32 (bool)
  const float* W1   = (const float*)d_in[2];   // [1024][1024]
  const float* b1   = (const float*)d_in[3];   // [1024]
  const float* w2   = (const float*)d_in[4];   // [1024]

  float* out    = (float*)d_out;
  float* u_last = out;                          // [128][1024]
  float* u_att  = out + BATCH * DIM;            // [128][1024]

  char* ws = (char*)d_ws;
  unsigned short* W1t = (unsigned short*)ws;                        // 2 MB
  float* scores = (float*)(ws + (size_t)DIM * DIM * 2);             // 256 KB

  hipMemsetAsync(scores, 0, MROWS * sizeof(float), stream);
  hipLaunchKernelGGL(w1t_kernel, dim3(256), dim3(256), 0, stream, W1, W1t);
  hipLaunchKernelGGL(gemm_score_kernel, dim3(4096), dim3(256), 0, stream,
                     X, W1t, b1, w2, scores);
  hipLaunchKernelGGL(attn_uatt_kernel, dim3(128, 2), dim3(256), 0, stream,
                     X, scores, mask, u_att, u_last);
}

// Round 17
// 276.154 us; speedup vs baseline: 1.0913x; 1.0913x over previous
//
#include <hip/hip_runtime.h>
#include <hip/hip_bf16.h>
#include <cstdint>
#include <cstddef>

// Problem constants (fixed by the reference)
#define BATCH 128
#define SEQ   512
#define DIM   1024
#define MROWS (BATCH * SEQ)          // 65536

typedef short short8 __attribute__((ext_vector_type(8)));
typedef __bf16 bf16x8 __attribute__((ext_vector_type(8)));
typedef float f32x4 __attribute__((ext_vector_type(4)));

// ---------- MFMA wrapper: accept either builtin signature (short8 or bf16x8) ----------
template <typename VA> struct other_frag { using type = bf16x8; };
template <> struct other_frag<bf16x8> { using type = short8; };

template <typename VA>
__device__ __forceinline__ auto try_mfma(VA a, VA b, f32x4 c, int)
    -> decltype(__builtin_amdgcn_mfma_f32_16x16x32_bf16(a, b, c, 0, 0, 0)) {
  return __builtin_amdgcn_mfma_f32_16x16x32_bf16(a, b, c, 0, 0, 0);
}
template <typename VA>
__device__ __forceinline__ f32x4 try_mfma(VA a, VA b, f32x4 c, long) {
  using O = typename other_frag<VA>::type;
  O a2 = __builtin_bit_cast(O, a);
  O b2 = __builtin_bit_cast(O, b);
  return __builtin_amdgcn_mfma_f32_16x16x32_bf16(a2, b2, c, 0, 0, 0);
}
__device__ __forceinline__ f32x4 mfma_bf16(short8 a, short8 b, f32x4 c) {
  return try_mfma(a, b, c, 0);
}

// ---------- helpers ----------
__device__ __forceinline__ unsigned short f32_to_bf16(float f) {
  union { float f; uint32_t u; } v; v.f = f;
  uint32_t u = v.u;
  u += 0x7FFFu + ((u >> 16) & 1u);   // round-to-nearest-even
  return (unsigned short)(u >> 16);
}

__device__ __forceinline__ float bf16_to_f32(unsigned short u) {
  union { uint32_t u; float f; } v; v.u = ((uint32_t)u) << 16; return v.f;
}

__device__ __forceinline__ void gload_lds16(const void* g, void* l) {
  __builtin_amdgcn_global_load_lds(
      (__attribute__((address_space(1))) void*)g,
      (__attribute__((address_space(3))) void*)l,
      16, 0, 0);
}

__device__ __forceinline__ float fast_tanh(float x) {
  x = fminf(fmaxf(x, -15.0f), 15.0f);
  float e = __expf(2.0f * x);
  return (e - 1.0f) / (e + 1.0f);
}

// ---------- kernel 1: cast X fp32 -> bf16, with fused u_last copy ----------
__global__ __launch_bounds__(256) void cast_x_kernel(const float* __restrict__ X,
                                                     unsigned short* __restrict__ Xb,
                                                     float* __restrict__ u_last) {
  const int total8 = MROWS * DIM / 8;        // 8388608 groups of 8
  int idx = blockIdx.x * 256 + threadIdx.x;
  const int stride = 2048 * 256;
  for (int i = idx; i < total8; i += stride) {
    const f32x4* p = (const f32x4*)X + (size_t)i * 2;
    f32x4 a = p[0];
    f32x4 b = p[1];
    short8 o;
    o[0] = (short)f32_to_bf16(a[0]); o[1] = (short)f32_to_bf16(a[1]);
    o[2] = (short)f32_to_bf16(a[2]); o[3] = (short)f32_to_bf16(a[3]);
    o[4] = (short)f32_to_bf16(b[0]); o[5] = (short)f32_to_bf16(b[1]);
    o[6] = (short)f32_to_bf16(b[2]); o[7] = (short)f32_to_bf16(b[3]);
    *((short8*)Xb + i) = o;
    int row = i >> 7;                 // global m-row of this 8-group
    if ((row & (SEQ - 1)) == SEQ - 1) {
      int g = i & 127;
      f32x4* dst = (f32x4*)(u_last + (size_t)(row >> 9) * DIM + g * 8);
      dst[0] = a;
      dst[1] = b;
    }
  }
}

// ---------- kernel 2: W1 (D x D) -> W1t bf16 (transposed, [e][d]) ----------
__global__ __launch_bounds__(256) void w1t_kernel(const float* __restrict__ W1,
                                                  unsigned short* __restrict__ W1t) {
  __shared__ float tile[64][65];
  int bx = blockIdx.x & 15;    // e-tile
  int by = blockIdx.x >> 4;    // d-tile
  int t = threadIdx.x;
  int c = t & 63, r0 = t >> 6;
#pragma unroll
  for (int i = 0; i < 16; i++) {
    int r = i * 4 + r0;
    tile[r][c] = W1[(size_t)(by * 64 + r) * DIM + bx * 64 + c];
  }
  __syncthreads();
#pragma unroll
  for (int i = 0; i < 16; i++) {
    int r = i * 4 + r0;
    W1t[(size_t)(bx * 64 + r) * DIM + by * 64 + c] = f32_to_bf16(tile[c][r]);
  }
}

// ---------- kernel 3: 256x256 GEMM, m201-style 8-phase BK=64 schedule ----------
// C[m][e] = sum_d Xb[m][d] * W1t[e][d]; scores[m] += sum_e tanh(C+b1[e])*w2[e]
//
// 8 waves (2M x 4N, wave tile 128x64).  K in tiles of 64; per tile 4 quadrant
// phases: {4 A ds_read_b128 (+8 B reads at ph0) || stage 1 half-tile (2
// global_load_lds) -> s_barrier -> setprio(1) 16 MFMA setprio(0) ->
// [ph3: vmcnt(6)] -> s_barrier}.  2 K-tile LDS buffers (128 KB).
//
// Consumption-ordered staging (race-free by trailing-barrier argument):
//   ph0: A-quad23(T+1) -> buf[(T+1)&1]  (that region last read at T-1 ph2-3)
//   ph1: B-h0(T+2)     -> buf[T&1]      (B(T) fully read into regs at ph0)
//   ph2: B-h1(T+2)     -> buf[T&1]
//   ph3: A-quad01(T+2) -> buf[T&1]      (A-quad01(T) read at ph0-1)
// vmcnt(6) at ph3-end retires exactly tile T+1's 4 halves (queue invariant:
// after wait, outstanding = {Bh0,Bh1,Aq01 of T+2} = 6 loads); prologue
// stages tile0 (8 loads) + {Bh0,Bh1,Aq01}(1) (6) then vmcnt(6); tails 0.
//
// LDS granule swizzle: tile [256 rows][64 k] bf16, 128-B stored row, granule
// js = q ^ F(row), F(row) = (row&7) ^ (((row>>3)&1)<<2).  Frag read (mi,kk):
// row = base+(lane&15), q' = kk*4 + (lane>>4): stride-8 lane groups hit 8
// DISTINCT granule columns (R10-validated bank model); staging applies the
// inverse on the global source, LDS dest linear per wave (1KB runs).
__global__ __launch_bounds__(512, 2) void gemm_score_kernel(
    const unsigned short* __restrict__ Xb,    // [MROWS][DIM] bf16
    const unsigned short* __restrict__ W1t,   // [DIM][DIM]  (e-major) bf16
    const float* __restrict__ b1,
    const float* __restrict__ w2,
    float* __restrict__ scores) {             // [MROWS]
  __shared__ __align__(16) char lds[131072];  // A: 2x32K [0,64K)  B: 2x32K [64K,128K)

  const int tid = threadIdx.x;
  const int lane = tid & 63;
  const int w = tid >> 6;                     // wave 0..7
  const int wr = w >> 2, wc = w & 3;          // 2 x 4 wave grid, 128x64 each

  // chunked XCD swizzle: 1024 blocks, 8 XCDs, n-fastest within each chunk
  const int bx = blockIdx.x;
  const int swz = (bx & 7) * 128 + (bx >> 3);
  const int m0 = (swz >> 2) * 256;
  const int n0 = (swz & 3) * 256;

#define FROW(r) (((r) & 7) ^ ((((r) >> 3) & 1) << 2))

  // ---- staging: per (half, i) source pointer; sc = i*512 + tid
  // rr = sc>>3, js = sc&7, row = rowMap(rr), q = js ^ F(row)
  // halves: AQ01 rows {0-63,128-191}: row = rr + (rr&64)
  //         AQ23 rows {64-127,192-255}: row = 64 + rr + (rr&64)
  //         BH0 rows 0-127: row = rr ;  BH1: row = 128 + rr
  const unsigned short *pAQ01[2], *pAQ23[2], *pBH0[2], *pBH1[2];
#pragma unroll
  for (int i = 0; i < 2; i++) {
    int sc = i * 512 + tid;
    int rr = sc >> 3, js = sc & 7;
    int rA01 = rr + (rr & 64);
    int rA23 = 64 + rr + (rr & 64);
    int rB0 = rr;
    int rB1 = 128 + rr;
    pAQ01[i] = Xb  + (size_t)(m0 + rA01) * DIM + (js ^ FROW(rA01)) * 8;
    pAQ23[i] = Xb  + (size_t)(m0 + rA23) * DIM + (js ^ FROW(rA23)) * 8;
    pBH0[i]  = W1t + (size_t)(n0 + rB0) * DIM + (js ^ FROW(rB0)) * 8;
    pBH1[i]  = W1t + (size_t)(n0 + rB1) * DIM + (js ^ FROW(rB1)) * 8;
  }
  // LDS dest row-starts (lane-0 of wave, per i): rr0 = i*64 + w*8
  int dA01[2], dA23[2], dB0[2], dB1[2];
#pragma unroll
  for (int i = 0; i < 2; i++) {
    int rr0 = i * 64 + w * 8;
    dA01[i] = (rr0 + (rr0 & 64)) * 128;
    dA23[i] = (64 + rr0 + (rr0 & 64)) * 128;
    dB0[i] = rr0 * 128;
    dB1[i] = (128 + rr0) * 128;
  }

  // ---- fragment LDS byte offsets
  int aOff[8][2];
#pragma unroll
  for (int mi = 0; mi < 8; mi++) {
    int row = wr * 128 + mi * 16 + (lane & 15);
#pragma unroll
    for (int kk = 0; kk < 2; kk++) {
      int js = (kk * 4 + (lane >> 4)) ^ FROW(row);
      aOff[mi][kk] = row * 128 + js * 16;
    }
  }
  int bOff[4][2];
#pragma unroll
  for (int ni = 0; ni < 4; ni++) {
    int row = wc * 64 + ni * 16 + (lane & 15);
#pragma unroll
    for (int kk = 0; kk < 2; kk++) {
      int js = (kk * 4 + (lane >> 4)) ^ FROW(row);
      bOff[ni][kk] = row * 128 + js * 16;
    }
  }

  f32x4 acc[8][4];
#pragma unroll
  for (int mi = 0; mi < 8; mi++)
#pragma unroll
    for (int ni = 0; ni < 4; ni++)
      acc[mi][ni] = (f32x4){0.f, 0.f, 0.f, 0.f};

  short8 bfv[4][2];

#define ST_AQ01(T, BUF) do {                                            \
    gload_lds16(pAQ01[0] + (T) * 64, lds + (BUF) * 32768 + dA01[0]);    \
    gload_lds16(pAQ01[1] + (T) * 64, lds + (BUF) * 32768 + dA01[1]);    \
  } while (0)
#define ST_AQ23(T, BUF) do {                                            \
    gload_lds16(pAQ23[0] + (T) * 64, lds + (BUF) * 32768 + dA23[0]);    \
    gload_lds16(pAQ23[1] + (T) * 64, lds + (BUF) * 32768 + dA23[1]);    \
  } while (0)
#define ST_BH0(T, BUF) do {                                             \
    gload_lds16(pBH0[0] + (T) * 64, lds + 65536 + (BUF) * 32768 + dB0[0]); \
    gload_lds16(pBH0[1] + (T) * 64, lds + 65536 + (BUF) * 32768 + dB0[1]); \
  } while (0)
#define ST_BH1(T, BUF) do {                                             \
    gload_lds16(pBH1[0] + (T) * 64, lds + 65536 + (BUF) * 32768 + dB1[0]); \
    gload_lds16(pBH1[1] + (T) * 64, lds + 65536 + (BUF) * 32768 + dB1[1]); \
  } while (0)

  // PHASE(T, BUF, Q, STAGE): reads+stage -> barrier -> MFMA -> [WAIT] -> barrier
#define PHASE(T, BUF, Q, STAGE, WAIT) do {                              \
    const char* bufA_ = lds + (BUF) * 32768;                            \
    short8 af0_ = *(const short8*)(bufA_ + aOff[2 * (Q)][0]);           \
    short8 af1_ = *(const short8*)(bufA_ + aOff[2 * (Q)][1]);           \
    short8 af2_ = *(const short8*)(bufA_ + aOff[2 * (Q) + 1][0]);       \
    short8 af3_ = *(const short8*)(bufA_ + aOff[2 * (Q) + 1][1]);       \
    if ((Q) == 0) {                                                     \
      const char* bufB_ = lds + 65536 + (BUF) * 32768;                  \
      _Pragma("unroll")                                                 \
      for (int ni = 0; ni < 4; ni++) {                                  \
        bfv[ni][0] = *(const short8*)(bufB_ + bOff[ni][0]);             \
        bfv[ni][1] = *(const short8*)(bufB_ + bOff[ni][1]);             \
      }                                                                 \
    }                                                                   \
    STAGE;                                                              \
    __builtin_amdgcn_s_barrier();                                       \
    __builtin_amdgcn_s_setprio(1);                                      \
    _Pragma("unroll")                                                   \
    for (int ni = 0; ni < 4; ni++) {                                    \
      acc[2 * (Q)][ni] = mfma_bf16(af0_, bfv[ni][0], acc[2 * (Q)][ni]); \
      acc[2 * (Q)][ni] = mfma_bf16(af1_, bfv[ni][1], acc[2 * (Q)][ni]); \
      acc[2 * (Q) + 1][ni] = mfma_bf16(af2_, bfv[ni][0], acc[2 * (Q) + 1][ni]); \
      acc[2 * (Q) + 1][ni] = mfma_bf16(af3_, bfv[ni][1], acc[2 * (Q) + 1][ni]); \
    }                                                                   \
    __builtin_amdgcn_s_setprio(0);                                      \
    WAIT;                                                               \
    __builtin_amdgcn_s_barrier();                                       \
  } while (0)

#define NOP_ do {} while (0)
#define WAIT6 asm volatile("s_waitcnt vmcnt(6)" ::: "memory")
#define WAIT0 asm volatile("s_waitcnt vmcnt(0)" ::: "memory")

  // TILE with full staging (valid for T <= 13)
#define TILE_FULL(T, BUF, OBUF) do {                                    \
    PHASE(T, BUF, 0, ST_AQ23((T) + 1, OBUF), NOP_);                     \
    PHASE(T, BUF, 1, ST_BH0((T) + 2, BUF), NOP_);                       \
    PHASE(T, BUF, 2, ST_BH1((T) + 2, BUF), NOP_);                       \
    PHASE(T, BUF, 3, ST_AQ01((T) + 2, BUF), WAIT6);                     \
  } while (0)

  // ---- prologue: tile0 all 4 halves; tile1 Bh0,Bh1,Aq01 (Aq23(1) at T0 ph0)
  ST_AQ01(0, 0); ST_AQ23(0, 0); ST_BH0(0, 0); ST_BH1(0, 0);
  ST_BH0(1, 1);  ST_BH1(1, 1);  ST_AQ01(1, 1);
  WAIT6;
  __builtin_amdgcn_s_barrier();

  // ---- main: tiles 0..13 fully staged
  for (int t = 0; t < 7; ++t) {
    const int T0 = 2 * t;
    TILE_FULL(T0, 0, 1);
    TILE_FULL(T0 + 1, 1, 0);
  }
  // tile 14: only ph0 stage (Aq23(15)); drain at ph3
  PHASE(14, 0, 0, ST_AQ23(15, 1), NOP_);
  PHASE(14, 0, 1, NOP_, NOP_);
  PHASE(14, 0, 2, NOP_, NOP_);
  PHASE(14, 0, 3, NOP_, WAIT0);
  // tile 15: no stages, no waits
  PHASE(15, 1, 0, NOP_, NOP_);
  PHASE(15, 1, 1, NOP_, NOP_);
  PHASE(15, 1, 2, NOP_, NOP_);
  PHASE(15, 1, 3, NOP_, NOP_);

#undef TILE_FULL
#undef PHASE
#undef ST_AQ01
#undef ST_AQ23
#undef ST_BH0
#undef ST_BH1

  // epilogue: scores[row] += sum over this wave's 64 cols of tanh(c + b1) * w2
  const int cg = lane >> 4;   // row group: rows cg*4 + j
  const int cl = lane & 15;   // col within fragment
#pragma unroll
  for (int mi = 0; mi < 8; mi++) {
    float p0 = 0.f, p1 = 0.f, p2 = 0.f, p3 = 0.f;
#pragma unroll
    for (int ni = 0; ni < 4; ni++) {
      int col = n0 + wc * 64 + ni * 16 + cl;
      float w2v = w2[col];
      float b1v = b1[col];
      p0 += fast_tanh(acc[mi][ni][0] + b1v) * w2v;
      p1 += fast_tanh(acc[mi][ni][1] + b1v) * w2v;
      p2 += fast_tanh(acc[mi][ni][2] + b1v) * w2v;
      p3 += fast_tanh(acc[mi][ni][3] + b1v) * w2v;
    }
#pragma unroll
    for (int off = 1; off < 16; off <<= 1) {
      p0 += __shfl_xor(p0, off);
      p1 += __shfl_xor(p1, off);
      p2 += __shfl_xor(p2, off);
      p3 += __shfl_xor(p3, off);
    }
    if (cl == 0) {
      int row = m0 + wr * 128 + mi * 16 + cg * 4;
      atomicAdd(&scores[row + 0], p0);
      atomicAdd(&scores[row + 1], p1);
      atomicAdd(&scores[row + 2], p2);
      atomicAdd(&scores[row + 3], p3);
    }
  }
}

// ---------- kernel 4: masked softmax + u_att (reads bf16 Xb) ----------
__global__ __launch_bounds__(256) void attn_uatt_kernel(
    const unsigned short* __restrict__ Xb,
    const float* __restrict__ scores,
    const int* __restrict__ mask,
    float* __restrict__ u_att) {
  const int b = blockIdx.x;
  const int half = blockIdx.y;            // d-range [half*512, half*512+512)
  const int tid = threadIdx.x;
  const int lane = tid & 63;
  const int wave = tid >> 6;

  __shared__ float attn[SEQ];
  __shared__ float rbuf[4];
  __shared__ float part[3][64 * 9];       // padded stride 9

  float s0 = scores[(size_t)b * SEQ + tid];
  float s1 = scores[(size_t)b * SEQ + 256 + tid];
  if (mask[(size_t)b * SEQ + tid]) s0 = -1000000000.0f;
  if (mask[(size_t)b * SEQ + 256 + tid]) s1 = -1000000000.0f;

  float mx = fmaxf(s0, s1);
#pragma unroll
  for (int off = 1; off < 64; off <<= 1) mx = fmaxf(mx, __shfl_xor(mx, off));
  if (lane == 0) rbuf[wave] = mx;
  __syncthreads();
  mx = fmaxf(fmaxf(rbuf[0], rbuf[1]), fmaxf(rbuf[2], rbuf[3]));

  float p0 = expf(s0 - mx), p1 = expf(s1 - mx);
  float sm = p0 + p1;
#pragma unroll
  for (int off = 1; off < 64; off <<= 1) sm += __shfl_xor(sm, off);
  __syncthreads();
  if (lane == 0) rbuf[wave] = sm;
  __syncthreads();
  sm = rbuf[0] + rbuf[1] + rbuf[2] + rbuf[3];
  float inv = 1.0f / sm;
  attn[tid] = p0 * inv;
  attn[tid + 256] = p1 * inv;
  __syncthreads();

  // u_att[b][d] = sum_s attn[s] * X[b][s][d]; block covers 512 d (64 chunks of 8)
  const int col = tid & 63;            // 8-bf16 chunk within the half
  const int sh = tid >> 6;             // s-range split: [sh*128, sh*128+128)
  const short8* Xp = (const short8*)Xb + (size_t)b * SEQ * (DIM / 8) + half * 64 + col;
  float a[8] = {0.f, 0.f, 0.f, 0.f, 0.f, 0.f, 0.f, 0.f};
  for (int s = sh * 128; s < sh * 128 + 128; s++) {
    short8 v = Xp[(size_t)s * (DIM / 8)];
    float wgt = attn[s];
#pragma unroll
    for (int j = 0; j < 8; j++)
      a[j] += wgt * bf16_to_f32((unsigned short)v[j]);
  }
  if (sh) {
#pragma unroll
    for (int j = 0; j < 8; j++) part[sh - 1][col * 9 + j] = a[j];
  }
  __syncthreads();
  if (sh == 0) {
#pragma unroll
    for (int j = 0; j < 8; j++)
      a[j] += part[0][col * 9 + j] + part[1][col * 9 + j] + part[2][col * 9 + j];
    f32x4 lo = {a[0], a[1], a[2], a[3]};
    f32x4 hi = {a[4], a[5], a[6], a[7]};
    f32x4* dst = (f32x4*)(u_att + (size_t)b * DIM + half * 512 + col * 8);
    dst[0] = lo;
    dst[1] = hi;
  }
}

// ---------- launcher ----------
extern "C" void kernel_launch(void* const* d_in, const int* in_sizes, int n_in,
                              void* d_out, int out_size, void* d_ws, size_t ws_size,
                              hipStream_t stream) {
  const float* X    = (const float*)d_in[0];   // [128][512][1024] fp32
  const int*   mask = (const int*)d_in[1];     // [128][512] int32 (bool)
  const float* W1   = (const float*)d_in[2];   // [1024][1024]
  const float* b1   = (const float*)d_in[3];   // [1024]
  const float* w2   = (const float*)d_in[4];   // [1024]

  float* out    = (float*)d_out;
  float* u_last = out;                          // [128][1024]
  float* u_att  = out + BATCH * DIM;            // [128][1024]

  char* ws = (char*)d_ws;
  unsigned short* Xb  = (unsigned short*)ws;                                // 128 MB
  unsigned short* W1t = (unsigned short*)(ws + (size_t)MROWS * DIM * 2);    // 2 MB
  float* scores = (float*)(ws + (size_t)MROWS * DIM * 2 + (size_t)DIM * DIM * 2); // 256 KB

  hipMemsetAsync(scores, 0, MROWS * sizeof(float), stream);
  hipLaunchKernelGGL(cast_x_kernel, dim3(2048), dim3(256), 0, stream, X, Xb, u_last);
  hipLaunchKernelGGL(w1t_kernel, dim3(256), dim3(256), 0, stream, W1, W1t);
  hipLaunchKernelGGL(gemm_score_kernel, dim3(1024), dim3(512), 0, stream,
                     Xb, W1t, b1, w2, scores);
  hipLaunchKernelGGL(attn_uatt_kernel, dim3(128, 2), dim3(256), 0, stream,
                     Xb, scores, mask, u_att);
}